// Round 3
// baseline (453.327 us; speedup 1.0000x reference)
//
#include <hip/hip_runtime.h>
#include <math.h>

#define D 128
#define NG 128
#define SLOTS 64

typedef __attribute__((ext_vector_type(8))) unsigned short u16x8;
typedef __attribute__((ext_vector_type(8))) short bf16x8;
typedef __attribute__((ext_vector_type(4))) float f32x4;

__device__ __forceinline__ float bf2f(unsigned short u) {
  return __uint_as_float(((unsigned int)u) << 16);
}
__device__ __forceinline__ unsigned short f2bf(float f) {
  unsigned int u = __float_as_uint(f);
  u += 0x7FFFu + ((u >> 16) & 1u);  // round-to-nearest-even
  return (unsigned short)(u >> 16);
}

// ---------------- fake-quant (per-tensor symmetric int4) -> bf16 ----------------
__global__ __launch_bounds__(256) void quant_kernel(
    const float* __restrict__ w0, const float* __restrict__ w1,
    const float* __restrict__ w2, const float* __restrict__ w3,
    const float* __restrict__ w4, const float* __restrict__ w5,
    unsigned short* __restrict__ qout) {
  const float* w;
  switch (blockIdx.x) {
    case 0: w = w0; break;
    case 1: w = w1; break;
    case 2: w = w2; break;
    case 3: w = w3; break;
    case 4: w = w4; break;
    default: w = w5; break;
  }
  unsigned short* q = qout + (size_t)blockIdx.x * (D * D);
  __shared__ float red[256];
  float m = 0.f;
  for (int i = threadIdx.x; i < D * D; i += 256) m = fmaxf(m, fabsf(w[i]));
  red[threadIdx.x] = m;
  __syncthreads();
  for (int s = 128; s > 0; s >>= 1) {
    if (threadIdx.x < s) red[threadIdx.x] = fmaxf(red[threadIdx.x], red[threadIdx.x + s]);
    __syncthreads();
  }
  float s = red[0] / 7.0f;
  for (int i = threadIdx.x; i < D * D; i += 256) {
    float r = rintf(w[i] / s);  // jnp.round == round-half-even
    r = fminf(fmaxf(r, -8.f), 7.f);
    q[i] = f2bf((s > 0.f) ? r * s : 0.f);
  }
}

// ---------------- x (f32) -> bf16, and zero the slot counters ----------------
__global__ __launch_bounds__(256) void convert_zero_kernel(const float* __restrict__ x,
                                                           unsigned short* __restrict__ o, int n8,
                                                           int* __restrict__ cnt, int N) {
  int i = blockIdx.x * 256 + threadIdx.x;
  if (i < N) cnt[i] = 0;
  if (i >= n8) return;
  const float4* xp = reinterpret_cast<const float4*>(x) + (size_t)i * 2;
  float4 a = xp[0], b = xp[1];
  u16x8 v;
  v[0] = f2bf(a.x); v[1] = f2bf(a.y); v[2] = f2bf(a.z); v[3] = f2bf(a.w);
  v[4] = f2bf(b.x); v[5] = f2bf(b.y); v[6] = f2bf(b.z); v[7] = f2bf(b.w);
  *(reinterpret_cast<u16x8*>(o) + i) = v;
}

// ---------------- slot-bucket build, XCD-partitioned by dst range ----------------
// blockIdx&7 is (heuristically) the XCD; each team only writes its own dst range,
// so each esrc cache line is dirtied in exactly one XCD's L2.
__global__ __launch_bounds__(256) void build_slots(const int* __restrict__ dst,
                                                   const int* __restrict__ src,
                                                   int* __restrict__ cnt, int* __restrict__ esrc,
                                                   int E, int per_team) {
  int team = blockIdx.x & 7;
  int tb = blockIdx.x >> 3;
  int nb = gridDim.x >> 3;
  int lo = team * per_team;
  int hi = lo + per_team;
  for (int e = tb * 256 + threadIdx.x; e < E; e += nb * 256) {
    int d = dst[e];
    if (d >= lo && d < hi) {
      int slot = atomicAdd(&cnt[d], 1);
      if (slot < SLOTS) esrc[(size_t)d * SLOTS + slot] = src[e];
    }
  }
}

// ---------------- fused GIN layer: out = MLP(h + sum_nbr h) ----------------
// Per block: 64 nodes. LDS: W1 (32K) + W2 (32K) + As tile (16K) = 80K -> 2 blocks/CU.
__global__ __launch_bounds__(256, 2) void layer_kernel(
    const unsigned short* __restrict__ h, const int* __restrict__ cnt,
    const int* __restrict__ esrc, const unsigned short* __restrict__ W1q,
    const float* __restrict__ b1, const unsigned short* __restrict__ W2q,
    const float* __restrict__ b2, unsigned short* __restrict__ out, int N, int relu_out) {
  __shared__ unsigned short Ws1[128 * 128];
  __shared__ unsigned short Ws2[128 * 128];
  __shared__ unsigned short As[64 * 128];
  const int tid = threadIdx.x;

  // stage W1, W2 with granule swizzle gs = g ^ (row&15)
#pragma unroll
  for (int i = 0; i < 8; i++) {
    int gid = tid + 256 * i;
    int row = gid >> 4;
    int g = gid & 15;
    int gs = g ^ (row & 15);
    u16x8 v1 = *reinterpret_cast<const u16x8*>(W1q + (size_t)row * D + g * 8);
    *reinterpret_cast<u16x8*>(&Ws1[row * D + gs * 8]) = v1;
    u16x8 v2 = *reinterpret_cast<const u16x8*>(W2q + (size_t)row * D + g * 8);
    *reinterpret_cast<u16x8*>(&Ws2[row * D + gs * 8]) = v2;
  }

  // aggregate 64 nodes into As (bf16), f32 accumulate
  {
    int x = tid & 15;   // granule
    int ty = tid >> 4;  // row group
    const u16x8* hp = reinterpret_cast<const u16x8*>(h);
#pragma unroll
    for (int rr = 0; rr < 4; rr++) {
      int row = ty + rr * 16;
      int node = blockIdx.x * 64 + row;
      u16x8 r;
      if (node < N) {
        u16x8 v = hp[(size_t)node * 16 + x];
        float acc[8];
#pragma unroll
        for (int i = 0; i < 8; i++) acc[i] = bf2f(v[i]);
        int c = cnt[node];
        if (c > SLOTS) c = SLOTS;
        const int* base = esrc + (size_t)node * SLOTS;
        for (int e = 0; e < c; ++e) {
          int s = base[e];
          u16x8 wv = hp[(size_t)s * 16 + x];
#pragma unroll
          for (int i = 0; i < 8; i++) acc[i] += bf2f(wv[i]);
        }
#pragma unroll
        for (int i = 0; i < 8; i++) r[i] = f2bf(acc[i]);
      } else {
#pragma unroll
        for (int i = 0; i < 8; i++) r[i] = 0;
      }
      int gs = x ^ (row & 15);
      *reinterpret_cast<u16x8*>(&As[row * D + gs * 8]) = r;
    }
  }
  __syncthreads();

  const int lane = tid & 63;
  const int w = tid >> 6;   // wave id: rows w*16..w*16+15
  const int c = lane & 15;
  const int q = lane >> 4;

  // GEMM1: acc1 = As @ W1^T
  f32x4 acc1[8] = {};
#pragma unroll
  for (int ks = 0; ks < 4; ks++) {
    int arow = w * 16 + c;
    int g = ks * 4 + q;
    bf16x8 a = *reinterpret_cast<const bf16x8*>(&As[arow * D + (g ^ (arow & 15)) * 8]);
#pragma unroll
    for (int j = 0; j < 8; j++) {
      int brow = j * 16 + c;
      bf16x8 b = *reinterpret_cast<const bf16x8*>(&Ws1[brow * D + (g ^ (brow & 15)) * 8]);
      acc1[j] = __builtin_amdgcn_mfma_f32_16x16x32_bf16(a, b, acc1[j], 0, 0, 0);
    }
  }

  // h1 = relu(acc1 + b1) -> write back into As (each wave touches only its own 16 rows)
#pragma unroll
  for (int j = 0; j < 8; j++) {
    int col = j * 16 + c;
    float bb = b1[col];
    int g = col >> 3;  // = 2j + (c>>3)
#pragma unroll
    for (int r = 0; r < 4; r++) {
      int row = w * 16 + q * 4 + r;
      float v = fmaxf(acc1[j][r] + bb, 0.f);
      As[row * D + ((g ^ (row & 15)) * 8) + (c & 7)] = f2bf(v);
    }
  }
  asm volatile("s_waitcnt lgkmcnt(0)" ::: "memory");
  __builtin_amdgcn_sched_barrier(0);

  // GEMM2: acc2 = h1 @ W2^T
  f32x4 acc2[8] = {};
#pragma unroll
  for (int ks = 0; ks < 4; ks++) {
    int arow = w * 16 + c;
    int g = ks * 4 + q;
    bf16x8 a = *reinterpret_cast<const bf16x8*>(&As[arow * D + (g ^ (arow & 15)) * 8]);
#pragma unroll
    for (int j = 0; j < 8; j++) {
      int brow = j * 16 + c;
      bf16x8 b = *reinterpret_cast<const bf16x8*>(&Ws2[brow * D + (g ^ (brow & 15)) * 8]);
      acc2[j] = __builtin_amdgcn_mfma_f32_16x16x32_bf16(a, b, acc2[j], 0, 0, 0);
    }
  }

  // epilogue: out = (relu?) (acc2 + b2)
#pragma unroll
  for (int j = 0; j < 8; j++) {
    int col = j * 16 + c;
    float bb = b2[col];
#pragma unroll
    for (int r = 0; r < 4; r++) {
      int node = blockIdx.x * 64 + w * 16 + q * 4 + r;
      if (node < N) {
        float v = acc2[j][r] + bb;
        if (relu_out) v = fmaxf(v, 0.f);
        out[(size_t)node * D + col] = f2bf(v);
      }
    }
  }
}

// ---------------- graph mean pool (bf16 in, f32 out; batch sorted) ----------------
__global__ __launch_bounds__(256) void pool_kernel(const unsigned short* __restrict__ h,
                                                   const int* __restrict__ batch, int n,
                                                   float* __restrict__ out) {
  int g = blockIdx.x;
  __shared__ int sbeg, send;
  if (threadIdx.x == 0) {
    int lo = 0, hi = n;
    while (lo < hi) { int mid = (lo + hi) >> 1; if (batch[mid] < g) lo = mid + 1; else hi = mid; }
    sbeg = lo;
    hi = n;
    while (lo < hi) { int mid = (lo + hi) >> 1; if (batch[mid] < g + 1) lo = mid + 1; else hi = mid; }
    send = lo;
  }
  __syncthreads();
  int beg = sbeg, end = send;
  int x = threadIdx.x & 15;
  int ty = threadIdx.x >> 4;
  const u16x8* hp = reinterpret_cast<const u16x8*>(h);
  float acc[8] = {};
  for (int i = beg + ty; i < end; i += 16) {
    u16x8 v = hp[(size_t)i * 16 + x];
#pragma unroll
    for (int k = 0; k < 8; k++) acc[k] += bf2f(v[k]);
  }
  __shared__ float red[16][16][8];
#pragma unroll
  for (int k = 0; k < 8; k++) red[ty][x][k] = acc[k];
  __syncthreads();
  for (int s = 8; s > 0; s >>= 1) {
    if (ty < s) {
#pragma unroll
      for (int k = 0; k < 8; k++) red[ty][x][k] += red[ty + s][x][k];
    }
    __syncthreads();
  }
  if (ty == 0) {
    float inv = 1.0f / fmaxf((float)(end - beg), 1.0f);
#pragma unroll
    for (int k = 0; k < 8; k++) out[(size_t)g * D + x * 8 + k] = red[0][x][k] * inv;
  }
}

extern "C" void kernel_launch(void* const* d_in, const int* in_sizes, int n_in,
                              void* d_out, int out_size, void* d_ws, size_t ws_size,
                              hipStream_t stream) {
  const float* x = (const float*)d_in[0];
  const int* ei = (const int*)d_in[1];
  const int* batch = (const int*)d_in[2];
  const float* w[6] = {(const float*)d_in[3], (const float*)d_in[5],
                       (const float*)d_in[7], (const float*)d_in[9],
                       (const float*)d_in[11], (const float*)d_in[13]};
  const float* b[6] = {(const float*)d_in[4], (const float*)d_in[6],
                       (const float*)d_in[8], (const float*)d_in[10],
                       (const float*)d_in[12], (const float*)d_in[14]};
  const int N = in_sizes[0] / D;
  const int E = in_sizes[1] / 2;
  const int* src = ei;
  const int* dst = ei + E;

  char* ws = (char*)d_ws;
  size_t off = 0;
  auto carve = [&](size_t bytes) -> char* {
    char* p = ws + off;
    off = (off + bytes + 255) & ~(size_t)255;
    return p;
  };
  unsigned short* hA = (unsigned short*)carve((size_t)N * D * 2);
  unsigned short* hB = (unsigned short*)carve((size_t)N * D * 2);
  unsigned short* qw = (unsigned short*)carve(6 * D * D * 2);
  int* cnt = (int*)carve((size_t)N * 4);
  int* esrc = (int*)carve((size_t)N * SLOTS * 4);
  if (off > ws_size) return;

  // 1) quantize weights -> bf16
  quant_kernel<<<6, 256, 0, stream>>>(w[0], w[1], w[2], w[3], w[4], w[5], qw);

  // 2) x -> bf16 (also zeroes cnt)
  convert_zero_kernel<<<(N * D / 8 + 255) / 256, 256, 0, stream>>>(x, hA, N * D / 8, cnt, N);

  // 3) slot buckets, XCD-partitioned
  int per_team = (N + 7) / 8;
  build_slots<<<1024, 256, 0, stream>>>(dst, src, cnt, esrc, E, per_team);

  // 4) 3 fused GIN layers (ping-pong hA/hB)
  unsigned short* cur = hA;
  unsigned short* oth = hB;
  int grid = (N + 63) / 64;
  for (int l = 0; l < 3; ++l) {
    layer_kernel<<<grid, 256, 0, stream>>>(cur, cnt, esrc, qw + (size_t)(2 * l) * D * D, b[2 * l],
                                           qw + (size_t)(2 * l + 1) * D * D, b[2 * l + 1], oth, N,
                                           (l < 2) ? 1 : 0);
    unsigned short* t = cur; cur = oth; oth = t;
  }

  // 5) mean pool -> f32 out
  pool_kernel<<<NG, 256, 0, stream>>>(cur, batch, N, (float*)d_out);
}

// Round 4
// 322.953 us; speedup vs baseline: 1.4037x; 1.4037x over previous
//
#include <hip/hip_runtime.h>
#include <math.h>

#define D 128
#define NG 128
#define SLOTS 64

typedef __attribute__((ext_vector_type(8))) unsigned short u16x8;
typedef __attribute__((ext_vector_type(8))) short bf16x8;
typedef __attribute__((ext_vector_type(4))) float f32x4;

__device__ __forceinline__ float bf2f(unsigned short u) {
  return __uint_as_float(((unsigned int)u) << 16);
}
__device__ __forceinline__ unsigned short f2bf(float f) {
  unsigned int u = __float_as_uint(f);
  u += 0x7FFFu + ((u >> 16) & 1u);  // round-to-nearest-even
  return (unsigned short)(u >> 16);
}

// ---------------- fake-quant (per-tensor symmetric int4) -> bf16; also zero cnt --------
__global__ __launch_bounds__(256) void quant_zero_kernel(
    const float* __restrict__ w0, const float* __restrict__ w1,
    const float* __restrict__ w2, const float* __restrict__ w3,
    const float* __restrict__ w4, const float* __restrict__ w5,
    unsigned short* __restrict__ qout, int* __restrict__ cnt, int N) {
  int gi = blockIdx.x * 256 + threadIdx.x;
  if (gi < N) cnt[gi] = 0;
  if (blockIdx.x >= 6) return;
  const float* w;
  switch (blockIdx.x) {
    case 0: w = w0; break;
    case 1: w = w1; break;
    case 2: w = w2; break;
    case 3: w = w3; break;
    case 4: w = w4; break;
    default: w = w5; break;
  }
  unsigned short* q = qout + (size_t)blockIdx.x * (D * D);
  __shared__ float red[256];
  float m = 0.f;
  for (int i = threadIdx.x; i < D * D; i += 256) m = fmaxf(m, fabsf(w[i]));
  red[threadIdx.x] = m;
  __syncthreads();
  for (int s = 128; s > 0; s >>= 1) {
    if (threadIdx.x < s) red[threadIdx.x] = fmaxf(red[threadIdx.x], red[threadIdx.x + s]);
    __syncthreads();
  }
  float s = red[0] / 7.0f;
  for (int i = threadIdx.x; i < D * D; i += 256) {
    float r = rintf(w[i] / s);  // jnp.round == round-half-even
    r = fminf(fmaxf(r, -8.f), 7.f);
    q[i] = f2bf((s > 0.f) ? r * s : 0.f);
  }
}

// ---------------- x->bf16 convert + XCD-partitioned slot-bucket build ----------------
// Grid is a multiple of 8. Teams (blockIdx&7) scan all edges, each writes only its own
// dst range so each esrc/cnt line is dirtied in exactly one XCD's L2.
__global__ __launch_bounds__(256) void convert_build_kernel(
    const float* __restrict__ x, unsigned short* __restrict__ o, int n8,
    const int* __restrict__ dst, const int* __restrict__ src, int* __restrict__ cnt,
    int* __restrict__ esrc, int E, int per_team) {
  int i = blockIdx.x * 256 + threadIdx.x;
  if (i < n8) {
    const float4* xp = reinterpret_cast<const float4*>(x) + (size_t)i * 2;
    float4 a = xp[0], b = xp[1];
    u16x8 v;
    v[0] = f2bf(a.x); v[1] = f2bf(a.y); v[2] = f2bf(a.z); v[3] = f2bf(a.w);
    v[4] = f2bf(b.x); v[5] = f2bf(b.y); v[6] = f2bf(b.z); v[7] = f2bf(b.w);
    *(reinterpret_cast<u16x8*>(o) + i) = v;
  }
  int team = blockIdx.x & 7;
  int tb = blockIdx.x >> 3;
  int nb = gridDim.x >> 3;
  int lo = team * per_team;
  int hi = lo + per_team;
  for (int e = tb * 256 + threadIdx.x; e < E; e += nb * 256) {
    int d = dst[e];
    if (d >= lo && d < hi) {
      int slot = atomicAdd(&cnt[d], 1);
      if (slot < SLOTS) esrc[(size_t)d * SLOTS + slot] = src[e];
    }
  }
}

// ---------------- fused GIN layer: out = MLP(h + sum_nbr h) ----------------
// 64 nodes/block, 4 waves; wave w owns rows w*16..w*16+15.
// Aggregation accumulates directly in MFMA A-fragment layout:
//   lane l: row = l&15, granules g = (l>>4) + 4*ks  (k = g*8..g*8+7)
// W1/W2 consumed straight from global (L2-resident). Only LDS: 16KB h1 shuffle tile.
__global__ __launch_bounds__(256) void layer_kernel(
    const unsigned short* __restrict__ h, const int* __restrict__ cnt,
    const int* __restrict__ esrc, const unsigned short* __restrict__ W1,
    const float* __restrict__ b1, const unsigned short* __restrict__ W2,
    const float* __restrict__ b2, unsigned short* __restrict__ out, int N, int relu_out) {
  __shared__ unsigned short hs[4][16 * D];  // per-wave h1 tile, XOR-swizzled granules
  const int tid = threadIdx.x;
  const int lane = tid & 63;
  const int w = tid >> 6;
  const int c = lane & 15;  // A-row within wave tile / B column offset
  const int q = lane >> 4;  // 0..3

  const int node = blockIdx.x * 64 + w * 16 + c;

  // ---- aggregation into A-fragment registers (f32 accumulate) ----
  float acc[4][8];
  const u16x8* hp = reinterpret_cast<const u16x8*>(h);
  if (node < N) {
    size_t rb = (size_t)node * 16;
#pragma unroll
    for (int ks = 0; ks < 4; ks++) {
      u16x8 v = hp[rb + ks * 4 + q];
#pragma unroll
      for (int i = 0; i < 8; i++) acc[ks][i] = bf2f(v[i]);
    }
    int cdeg = cnt[node];
    if (cdeg > SLOTS) cdeg = SLOTS;
    const int* base = esrc + (size_t)node * SLOTS;
#pragma unroll 2
    for (int e = 0; e < cdeg; e++) {
      int s = base[e];
      size_t sb = (size_t)s * 16;
#pragma unroll
      for (int ks = 0; ks < 4; ks++) {
        u16x8 v = hp[sb + ks * 4 + q];
#pragma unroll
        for (int i = 0; i < 8; i++) acc[ks][i] += bf2f(v[i]);
      }
    }
  } else {
#pragma unroll
    for (int ks = 0; ks < 4; ks++)
#pragma unroll
      for (int i = 0; i < 8; i++) acc[ks][i] = 0.f;
  }

  bf16x8 afrag[4];
#pragma unroll
  for (int ks = 0; ks < 4; ks++) {
#pragma unroll
    for (int i = 0; i < 8; i++) afrag[ks][i] = (short)f2bf(acc[ks][i]);
  }

  // ---- GEMM1: C1 = A @ W1^T ----
  f32x4 acc1[8] = {};
#pragma unroll
  for (int ks = 0; ks < 4; ks++) {
    int g = ks * 4 + q;
#pragma unroll
    for (int j = 0; j < 8; j++) {
      bf16x8 b = *reinterpret_cast<const bf16x8*>(W1 + (size_t)(j * 16 + c) * D + g * 8);
      acc1[j] = __builtin_amdgcn_mfma_f32_16x16x32_bf16(afrag[ks], b, acc1[j], 0, 0, 0);
    }
  }

  // ---- h1 = relu(C1 + b1) -> per-wave LDS tile (C-layout -> A-layout shuffle) ----
  unsigned short* tile = &hs[w][0];
#pragma unroll
  for (int j = 0; j < 8; j++) {
    int col = j * 16 + c;
    float bb = b1[col];
    int gcol = col >> 3;
    int el = col & 7;
#pragma unroll
    for (int r = 0; r < 4; r++) {
      int row = q * 4 + r;  // C/D layout: row = (lane>>4)*4 + reg
      float v = fmaxf(acc1[j][r] + bb, 0.f);
      tile[row * D + ((gcol ^ row) * 8) + el] = f2bf(v);
    }
  }
  asm volatile("s_waitcnt lgkmcnt(0)" ::: "memory");
  __builtin_amdgcn_sched_barrier(0);  // wave-local RAW guard (guide rule #18)

  // ---- GEMM2: C2 = h1 @ W2^T ----
  f32x4 acc2[8] = {};
#pragma unroll
  for (int ks = 0; ks < 4; ks++) {
    int g = ks * 4 + q;
    bf16x8 a = *reinterpret_cast<const bf16x8*>(&tile[c * D + ((g ^ c) * 8)]);
#pragma unroll
    for (int j = 0; j < 8; j++) {
      bf16x8 b = *reinterpret_cast<const bf16x8*>(W2 + (size_t)(j * 16 + c) * D + g * 8);
      acc2[j] = __builtin_amdgcn_mfma_f32_16x16x32_bf16(a, b, acc2[j], 0, 0, 0);
    }
  }

  // ---- epilogue ----
#pragma unroll
  for (int j = 0; j < 8; j++) {
    int col = j * 16 + c;
    float bb = b2[col];
#pragma unroll
    for (int r = 0; r < 4; r++) {
      int rnode = blockIdx.x * 64 + w * 16 + q * 4 + r;
      if (rnode < N) {
        float v = acc2[j][r] + bb;
        if (relu_out) v = fmaxf(v, 0.f);
        out[(size_t)rnode * D + col] = f2bf(v);
      }
    }
  }
}

// ---------------- graph mean pool (bf16 in, f32 out; batch sorted) ----------------
__global__ __launch_bounds__(256) void pool_kernel(const unsigned short* __restrict__ h,
                                                   const int* __restrict__ batch, int n,
                                                   float* __restrict__ out) {
  int g = blockIdx.x;
  __shared__ int sbeg, send;
  if (threadIdx.x == 0) {
    int lo = 0, hi = n;
    while (lo < hi) { int mid = (lo + hi) >> 1; if (batch[mid] < g) lo = mid + 1; else hi = mid; }
    sbeg = lo;
    hi = n;
    while (lo < hi) { int mid = (lo + hi) >> 1; if (batch[mid] < g + 1) lo = mid + 1; else hi = mid; }
    send = lo;
  }
  __syncthreads();
  int beg = sbeg, end = send;
  int x = threadIdx.x & 15;
  int ty = threadIdx.x >> 4;
  const u16x8* hp = reinterpret_cast<const u16x8*>(h);
  float acc[8] = {};
  for (int i = beg + ty; i < end; i += 16) {
    u16x8 v = hp[(size_t)i * 16 + x];
#pragma unroll
    for (int k = 0; k < 8; k++) acc[k] += bf2f(v[k]);
  }
  __shared__ float red[16][16][8];
#pragma unroll
  for (int k = 0; k < 8; k++) red[ty][x][k] = acc[k];
  __syncthreads();
  for (int s = 8; s > 0; s >>= 1) {
    if (ty < s) {
#pragma unroll
      for (int k = 0; k < 8; k++) red[ty][x][k] += red[ty + s][x][k];
    }
    __syncthreads();
  }
  if (ty == 0) {
    float inv = 1.0f / fmaxf((float)(end - beg), 1.0f);
#pragma unroll
    for (int k = 0; k < 8; k++) out[(size_t)g * D + x * 8 + k] = red[0][x][k] * inv;
  }
}

extern "C" void kernel_launch(void* const* d_in, const int* in_sizes, int n_in,
                              void* d_out, int out_size, void* d_ws, size_t ws_size,
                              hipStream_t stream) {
  const float* x = (const float*)d_in[0];
  const int* ei = (const int*)d_in[1];
  const int* batch = (const int*)d_in[2];
  const float* w[6] = {(const float*)d_in[3], (const float*)d_in[5],
                       (const float*)d_in[7], (const float*)d_in[9],
                       (const float*)d_in[11], (const float*)d_in[13]};
  const float* b[6] = {(const float*)d_in[4], (const float*)d_in[6],
                       (const float*)d_in[8], (const float*)d_in[10],
                       (const float*)d_in[12], (const float*)d_in[14]};
  const int N = in_sizes[0] / D;
  const int E = in_sizes[1] / 2;
  const int* src = ei;
  const int* dst = ei + E;

  char* ws = (char*)d_ws;
  size_t off = 0;
  auto carve = [&](size_t bytes) -> char* {
    char* p = ws + off;
    off = (off + bytes + 255) & ~(size_t)255;
    return p;
  };
  unsigned short* hA = (unsigned short*)carve((size_t)N * D * 2);
  unsigned short* hB = (unsigned short*)carve((size_t)N * D * 2);
  unsigned short* qw = (unsigned short*)carve(6 * D * D * 2);
  int* cnt = (int*)carve((size_t)N * 4);
  int* esrc = (int*)carve((size_t)N * SLOTS * 4);
  if (off > ws_size) return;

  // 1) quantize weights -> bf16, zero cnt
  int qzGrid = (N + 255) / 256;
  if (qzGrid < 6) qzGrid = 6;
  quant_zero_kernel<<<qzGrid, 256, 0, stream>>>(w[0], w[1], w[2], w[3], w[4], w[5], qw, cnt, N);

  // 2) x->bf16 convert + XCD-partitioned slot build (one kernel)
  int n8 = N * D / 8;
  int cbGrid = (n8 + 255) / 256;
  int ebGrid = (E + 255) / 256;
  if (ebGrid > cbGrid) cbGrid = ebGrid;
  cbGrid = (cbGrid + 7) & ~7;  // multiple of 8 for exact team coverage
  int per_team = (N + 7) / 8;
  convert_build_kernel<<<cbGrid, 256, 0, stream>>>(x, hA, n8, dst, src, cnt, esrc, E, per_team);

  // 3) 3 fused GIN layers (ping-pong hA/hB)
  unsigned short* cur = hA;
  unsigned short* oth = hB;
  int grid = (N + 63) / 64;
  for (int l = 0; l < 3; ++l) {
    layer_kernel<<<grid, 256, 0, stream>>>(cur, cnt, esrc, qw + (size_t)(2 * l) * D * D, b[2 * l],
                                           qw + (size_t)(2 * l + 1) * D * D, b[2 * l + 1], oth, N,
                                           (l < 2) ? 1 : 0);
    unsigned short* t = cur; cur = oth; oth = t;
  }

  // 4) mean pool -> f32 out
  pool_kernel<<<NG, 256, 0, stream>>>(cur, batch, N, (float*)d_out);
}

// Round 5
// 289.191 us; speedup vs baseline: 1.5676x; 1.1167x over previous
//
#include <hip/hip_runtime.h>
#include <math.h>

#define D 128
#define NG 128
#define SLOTS 64

typedef __attribute__((ext_vector_type(8))) unsigned short u16x8;
typedef __attribute__((ext_vector_type(8))) short bf16x8;
typedef __attribute__((ext_vector_type(4))) float f32x4;

__device__ __forceinline__ float bf2f(unsigned short u) {
  return __uint_as_float(((unsigned int)u) << 16);
}
__device__ __forceinline__ unsigned short f2bf(float f) {
  unsigned int u = __float_as_uint(f);
  u += 0x7FFFu + ((u >> 16) & 1u);  // round-to-nearest-even
  return (unsigned short)(u >> 16);
}

// ---------------- fake-quant (per-tensor symmetric int4) -> bf16; also zero cnt --------
__global__ __launch_bounds__(256) void quant_zero_kernel(
    const float* __restrict__ w0, const float* __restrict__ w1,
    const float* __restrict__ w2, const float* __restrict__ w3,
    const float* __restrict__ w4, const float* __restrict__ w5,
    unsigned short* __restrict__ qout, int* __restrict__ cnt, int N) {
  int gi = blockIdx.x * 256 + threadIdx.x;
  if (gi < N) cnt[gi] = 0;
  if (blockIdx.x >= 6) return;
  const float* w;
  switch (blockIdx.x) {
    case 0: w = w0; break;
    case 1: w = w1; break;
    case 2: w = w2; break;
    case 3: w = w3; break;
    case 4: w = w4; break;
    default: w = w5; break;
  }
  unsigned short* q = qout + (size_t)blockIdx.x * (D * D);
  __shared__ float red[256];
  float m = 0.f;
  for (int i = threadIdx.x; i < D * D; i += 256) m = fmaxf(m, fabsf(w[i]));
  red[threadIdx.x] = m;
  __syncthreads();
  for (int s = 128; s > 0; s >>= 1) {
    if (threadIdx.x < s) red[threadIdx.x] = fmaxf(red[threadIdx.x], red[threadIdx.x + s]);
    __syncthreads();
  }
  float s = red[0] / 7.0f;
  for (int i = threadIdx.x; i < D * D; i += 256) {
    float r = rintf(w[i] / s);  // jnp.round == round-half-even
    r = fminf(fmaxf(r, -8.f), 7.f);
    q[i] = f2bf((s > 0.f) ? r * s : 0.f);
  }
}

// ---------------- x->bf16 convert + XCD-partitioned slot-bucket build ----------------
__global__ __launch_bounds__(256) void convert_build_kernel(
    const float* __restrict__ x, unsigned short* __restrict__ o, int n8,
    const int* __restrict__ dst, const int* __restrict__ src, int* __restrict__ cnt,
    int* __restrict__ esrc, int E, int per_team) {
  int i = blockIdx.x * 256 + threadIdx.x;
  if (i < n8) {
    const float4* xp = reinterpret_cast<const float4*>(x) + (size_t)i * 2;
    float4 a = xp[0], b = xp[1];
    u16x8 v;
    v[0] = f2bf(a.x); v[1] = f2bf(a.y); v[2] = f2bf(a.z); v[3] = f2bf(a.w);
    v[4] = f2bf(b.x); v[5] = f2bf(b.y); v[6] = f2bf(b.z); v[7] = f2bf(b.w);
    *(reinterpret_cast<u16x8*>(o) + i) = v;
  }
  int team = blockIdx.x & 7;
  int tb = blockIdx.x >> 3;
  int nb = gridDim.x >> 3;
  int lo = team * per_team;
  int hi = lo + per_team;
  for (int e = tb * 256 + threadIdx.x; e < E; e += nb * 256) {
    int d = dst[e];
    if (d >= lo && d < hi) {
      int slot = atomicAdd(&cnt[d], 1);
      if (slot < SLOTS) esrc[(size_t)d * SLOTS + slot] = src[e];
    }
  }
}

// ---------------- GIN aggregation (standalone, occupancy-maximized) ----------------
// 16 nodes/block, 256 threads: lane granule x=0..15 (16B), row y=0..15.
// Edge loop processed in pairs with independent loads for MLP.
__global__ __launch_bounds__(256) void aggregate_kernel(
    const unsigned short* __restrict__ h, const int* __restrict__ cnt,
    const int* __restrict__ esrc, unsigned short* __restrict__ out, int n) {
  int node = blockIdx.x * 16 + threadIdx.y;
  if (node >= n) return;
  int x = threadIdx.x;
  const u16x8* hp = reinterpret_cast<const u16x8*>(h);
  u16x8 v = hp[(size_t)node * 16 + x];
  float acc[8];
#pragma unroll
  for (int i = 0; i < 8; i++) acc[i] = bf2f(v[i]);
  int c = cnt[node];
  if (c > SLOTS) c = SLOTS;
  const int* base = esrc + (size_t)node * SLOTS;
  int e = 0;
#pragma unroll 2
  for (; e + 2 <= c; e += 2) {
    int s0 = base[e];
    int s1 = base[e + 1];
    u16x8 a0 = hp[(size_t)s0 * 16 + x];
    u16x8 a1 = hp[(size_t)s1 * 16 + x];
#pragma unroll
    for (int i = 0; i < 8; i++) acc[i] += bf2f(a0[i]);
#pragma unroll
    for (int i = 0; i < 8; i++) acc[i] += bf2f(a1[i]);
  }
  if (e < c) {
    u16x8 a0 = hp[(size_t)base[e] * 16 + x];
#pragma unroll
    for (int i = 0; i < 8; i++) acc[i] += bf2f(a0[i]);
  }
  u16x8 r;
#pragma unroll
  for (int i = 0; i < 8; i++) r[i] = f2bf(acc[i]);
  reinterpret_cast<u16x8*>(out)[(size_t)node * 16 + x] = r;
}

// ---------------- MLP: hio = (relu?)(relu(hio@W1^T+b1)@W2^T+b2), in-place ----------------
// 64 nodes/block, 4 waves; wave w owns rows w*16..w*16+15 (reads and writes only those).
// W1/W2 consumed from global (L1/L2-resident). LDS: 16KB per-wave h1 shuffle tile.
__global__ __launch_bounds__(256) void mlp_kernel(
    unsigned short* __restrict__ hio, const unsigned short* __restrict__ W1,
    const float* __restrict__ b1, const unsigned short* __restrict__ W2,
    const float* __restrict__ b2, int N, int relu_out) {
  __shared__ unsigned short hs[4][16 * D];
  const int tid = threadIdx.x;
  const int lane = tid & 63;
  const int w = tid >> 6;
  const int c = lane & 15;  // A row within wave tile / B column offset
  const int q = lane >> 4;  // 0..3

  const int node = blockIdx.x * 64 + w * 16 + c;

  // A-fragments straight from global: granule g = ks*4 + q of row node
  bf16x8 afrag[4];
  if (node < N) {
    const bf16x8* hp = reinterpret_cast<const bf16x8*>(hio);
    size_t rb = (size_t)node * 16;
#pragma unroll
    for (int ks = 0; ks < 4; ks++) afrag[ks] = hp[rb + ks * 4 + q];
  } else {
#pragma unroll
    for (int ks = 0; ks < 4; ks++)
#pragma unroll
      for (int i = 0; i < 8; i++) afrag[ks][i] = 0;
  }

  // GEMM1
  f32x4 acc1[8] = {};
#pragma unroll
  for (int ks = 0; ks < 4; ks++) {
    int g = ks * 4 + q;
#pragma unroll
    for (int j = 0; j < 8; j++) {
      bf16x8 b = *reinterpret_cast<const bf16x8*>(W1 + (size_t)(j * 16 + c) * D + g * 8);
      acc1[j] = __builtin_amdgcn_mfma_f32_16x16x32_bf16(afrag[ks], b, acc1[j], 0, 0, 0);
    }
  }

  // h1 = relu(acc1+b1) -> per-wave LDS tile (C-layout -> A-layout shuffle, XOR swizzle)
  unsigned short* tile = &hs[w][0];
#pragma unroll
  for (int j = 0; j < 8; j++) {
    int col = j * 16 + c;
    float bb = b1[col];
    int gcol = col >> 3;
    int el = col & 7;
#pragma unroll
    for (int r = 0; r < 4; r++) {
      int row = q * 4 + r;  // C/D layout: row = (lane>>4)*4 + reg
      float v = fmaxf(acc1[j][r] + bb, 0.f);
      tile[row * D + ((gcol ^ row) * 8) + el] = f2bf(v);
    }
  }
  asm volatile("s_waitcnt lgkmcnt(0)" ::: "memory");
  __builtin_amdgcn_sched_barrier(0);  // wave-local RAW guard (guide rule #18)

  // GEMM2
  f32x4 acc2[8] = {};
#pragma unroll
  for (int ks = 0; ks < 4; ks++) {
    int g = ks * 4 + q;
    bf16x8 a = *reinterpret_cast<const bf16x8*>(&tile[c * D + ((g ^ c) * 8)]);
#pragma unroll
    for (int j = 0; j < 8; j++) {
      bf16x8 b = *reinterpret_cast<const bf16x8*>(W2 + (size_t)(j * 16 + c) * D + g * 8);
      acc2[j] = __builtin_amdgcn_mfma_f32_16x16x32_bf16(a, b, acc2[j], 0, 0, 0);
    }
  }

  // epilogue (in-place write of the same 16 rows this wave read)
#pragma unroll
  for (int j = 0; j < 8; j++) {
    int col = j * 16 + c;
    float bb = b2[col];
#pragma unroll
    for (int r = 0; r < 4; r++) {
      int rnode = blockIdx.x * 64 + w * 16 + q * 4 + r;
      if (rnode < N) {
        float v = acc2[j][r] + bb;
        if (relu_out) v = fmaxf(v, 0.f);
        hio[(size_t)rnode * D + col] = f2bf(v);
      }
    }
  }
}

// ---------------- graph mean pool (bf16 in, f32 out; batch sorted) ----------------
__global__ __launch_bounds__(512) void pool_kernel(const unsigned short* __restrict__ h,
                                                   const int* __restrict__ batch, int n,
                                                   float* __restrict__ out) {
  int g = blockIdx.x;
  __shared__ int sbeg, send;
  if (threadIdx.x == 0) {
    int lo = 0, hi = n;
    while (lo < hi) { int mid = (lo + hi) >> 1; if (batch[mid] < g) lo = mid + 1; else hi = mid; }
    sbeg = lo;
    hi = n;
    while (lo < hi) { int mid = (lo + hi) >> 1; if (batch[mid] < g + 1) lo = mid + 1; else hi = mid; }
    send = lo;
  }
  __syncthreads();
  int beg = sbeg, end = send;
  int x = threadIdx.x & 15;
  int ty = threadIdx.x >> 4;  // 0..31
  const u16x8* hp = reinterpret_cast<const u16x8*>(h);
  float acc[8] = {};
  for (int i = beg + ty; i < end; i += 32) {
    u16x8 v = hp[(size_t)i * 16 + x];
#pragma unroll
    for (int k = 0; k < 8; k++) acc[k] += bf2f(v[k]);
  }
  __shared__ float red[32][16][8];
#pragma unroll
  for (int k = 0; k < 8; k++) red[ty][x][k] = acc[k];
  __syncthreads();
  for (int s = 16; s > 0; s >>= 1) {
    if (ty < s) {
#pragma unroll
      for (int k = 0; k < 8; k++) red[ty][x][k] += red[ty + s][x][k];
    }
    __syncthreads();
  }
  if (ty == 0) {
    float inv = 1.0f / fmaxf((float)(end - beg), 1.0f);
#pragma unroll
    for (int k = 0; k < 8; k++) out[(size_t)g * D + x * 8 + k] = red[0][x][k] * inv;
  }
}

extern "C" void kernel_launch(void* const* d_in, const int* in_sizes, int n_in,
                              void* d_out, int out_size, void* d_ws, size_t ws_size,
                              hipStream_t stream) {
  const float* x = (const float*)d_in[0];
  const int* ei = (const int*)d_in[1];
  const int* batch = (const int*)d_in[2];
  const float* w[6] = {(const float*)d_in[3], (const float*)d_in[5],
                       (const float*)d_in[7], (const float*)d_in[9],
                       (const float*)d_in[11], (const float*)d_in[13]};
  const float* b[6] = {(const float*)d_in[4], (const float*)d_in[6],
                       (const float*)d_in[8], (const float*)d_in[10],
                       (const float*)d_in[12], (const float*)d_in[14]};
  const int N = in_sizes[0] / D;
  const int E = in_sizes[1] / 2;
  const int* src = ei;
  const int* dst = ei + E;

  char* ws = (char*)d_ws;
  size_t off = 0;
  auto carve = [&](size_t bytes) -> char* {
    char* p = ws + off;
    off = (off + bytes + 255) & ~(size_t)255;
    return p;
  };
  unsigned short* hA = (unsigned short*)carve((size_t)N * D * 2);
  unsigned short* hB = (unsigned short*)carve((size_t)N * D * 2);
  unsigned short* qw = (unsigned short*)carve(6 * D * D * 2);
  int* cnt = (int*)carve((size_t)N * 4);
  int* esrc = (int*)carve((size_t)N * SLOTS * 4);
  if (off > ws_size) return;

  // 1) quantize weights -> bf16, zero cnt
  int qzGrid = (N + 255) / 256;
  if (qzGrid < 6) qzGrid = 6;
  quant_zero_kernel<<<qzGrid, 256, 0, stream>>>(w[0], w[1], w[2], w[3], w[4], w[5], qw, cnt, N);

  // 2) x->bf16 convert + XCD-partitioned slot build
  int n8 = N * D / 8;
  int cbGrid = (n8 + 255) / 256;
  int ebGrid = (E + 255) / 256;
  if (ebGrid > cbGrid) cbGrid = ebGrid;
  cbGrid = (cbGrid + 7) & ~7;
  int per_team = (N + 7) / 8;
  convert_build_kernel<<<cbGrid, 256, 0, stream>>>(x, hA, n8, dst, src, cnt, esrc, E, per_team);

  // 3) 3 layers: aggregate (ping-pong) then MLP in-place
  dim3 aggBlock(16, 16);
  int aggGrid = (N + 15) / 16;
  int mlpGrid = (N + 63) / 64;
  unsigned short* cur = hA;
  unsigned short* oth = hB;
  for (int l = 0; l < 3; ++l) {
    aggregate_kernel<<<aggGrid, aggBlock, 0, stream>>>(cur, cnt, esrc, oth, N);
    mlp_kernel<<<mlpGrid, 256, 0, stream>>>(oth, qw + (size_t)(2 * l) * D * D, b[2 * l],
                                            qw + (size_t)(2 * l + 1) * D * D, b[2 * l + 1], N,
                                            (l < 2) ? 1 : 0);
    unsigned short* t = cur; cur = oth; oth = t;
  }

  // 4) mean pool -> f32 out
  pool_kernel<<<NG, 512, 0, stream>>>(cur, batch, N, (float*)d_out);
}

// Round 6
// 225.788 us; speedup vs baseline: 2.0078x; 1.2808x over previous
//
#include <hip/hip_runtime.h>
#include <math.h>

#define D 128
#define NG 128
#define SLOTS 64

typedef __attribute__((ext_vector_type(8))) unsigned short u16x8;
typedef __attribute__((ext_vector_type(8))) short bf16x8;
typedef __attribute__((ext_vector_type(4))) float f32x4;

__device__ __forceinline__ float bf2f(unsigned short u) {
  return __uint_as_float(((unsigned int)u) << 16);
}
__device__ __forceinline__ unsigned short f2bf(float f) {
  unsigned int u = __float_as_uint(f);
  u += 0x7FFFu + ((u >> 16) & 1u);  // round-to-nearest-even
  return (unsigned short)(u >> 16);
}

// ---- prep: quant W->bf16 (blocks 0..5), zero cnt, convert x->bf16 ----
__global__ __launch_bounds__(256) void prep_kernel(
    const float* __restrict__ x, unsigned short* __restrict__ o, int n8,
    const float* __restrict__ w0, const float* __restrict__ w1,
    const float* __restrict__ w2, const float* __restrict__ w3,
    const float* __restrict__ w4, const float* __restrict__ w5,
    unsigned short* __restrict__ qout, int* __restrict__ cnt, int N) {
  int i = blockIdx.x * 256 + threadIdx.x;
  if (i < N) cnt[i] = 0;
  if (i < n8) {
    const float4* xp = reinterpret_cast<const float4*>(x) + (size_t)i * 2;
    float4 a = xp[0], b = xp[1];
    u16x8 v;
    v[0] = f2bf(a.x); v[1] = f2bf(a.y); v[2] = f2bf(a.z); v[3] = f2bf(a.w);
    v[4] = f2bf(b.x); v[5] = f2bf(b.y); v[6] = f2bf(b.z); v[7] = f2bf(b.w);
    *(reinterpret_cast<u16x8*>(o) + i) = v;
  }
  if (blockIdx.x < 6) {
    const float* w;
    switch (blockIdx.x) {
      case 0: w = w0; break;
      case 1: w = w1; break;
      case 2: w = w2; break;
      case 3: w = w3; break;
      case 4: w = w4; break;
      default: w = w5; break;
    }
    unsigned short* q = qout + (size_t)blockIdx.x * (D * D);
    __shared__ float red[256];
    float m = 0.f;
    for (int k = threadIdx.x; k < D * D; k += 256) m = fmaxf(m, fabsf(w[k]));
    red[threadIdx.x] = m;
    __syncthreads();
    for (int s = 128; s > 0; s >>= 1) {
      if (threadIdx.x < s) red[threadIdx.x] = fmaxf(red[threadIdx.x], red[threadIdx.x + s]);
      __syncthreads();
    }
    float s = red[0] / 7.0f;
    for (int k = threadIdx.x; k < D * D; k += 256) {
      float r = rintf(w[k] / s);  // jnp.round == round-half-even
      r = fminf(fmaxf(r, -8.f), 7.f);
      q[k] = f2bf((s > 0.f) ? r * s : 0.f);
    }
  }
}

// ---- slot-bucket build, XCD-partitioned by dst range (standalone: L2-resident) ----
__global__ __launch_bounds__(256) void build_kernel(const int* __restrict__ dst,
                                                    const int* __restrict__ src,
                                                    int* __restrict__ cnt, int* __restrict__ esrc,
                                                    int E, int per_team) {
  int team = blockIdx.x & 7;
  int tb = blockIdx.x >> 3;
  int nb = gridDim.x >> 3;
  int lo = team * per_team;
  int hi = lo + per_team;
  for (int e = tb * 256 + threadIdx.x; e < E; e += nb * 256) {
    int d = dst[e];
    if (d >= lo && d < hi) {
      int slot = atomicAdd(&cnt[d], 1);
      if (slot < SLOTS) esrc[(size_t)d * SLOTS + slot] = src[e];
    }
  }
}

// ---- GIN aggregation: out[n] = h[n] + sum_nbr h (unroll 4 for MLP) ----
__global__ __launch_bounds__(256) void aggregate_kernel(
    const unsigned short* __restrict__ h, const int* __restrict__ cnt,
    const int* __restrict__ esrc, unsigned short* __restrict__ out, int n) {
  int node = blockIdx.x * 16 + threadIdx.y;
  if (node >= n) return;
  int x = threadIdx.x;
  const u16x8* hp = reinterpret_cast<const u16x8*>(h);
  u16x8 v = hp[(size_t)node * 16 + x];
  float acc[8];
#pragma unroll
  for (int i = 0; i < 8; i++) acc[i] = bf2f(v[i]);
  int c = cnt[node];
  if (c > SLOTS) c = SLOTS;
  const int* base = esrc + (size_t)node * SLOTS;
  int e = 0;
  for (; e + 4 <= c; e += 4) {
    int s0 = base[e], s1 = base[e + 1], s2 = base[e + 2], s3 = base[e + 3];
    u16x8 a0 = hp[(size_t)s0 * 16 + x];
    u16x8 a1 = hp[(size_t)s1 * 16 + x];
    u16x8 a2 = hp[(size_t)s2 * 16 + x];
    u16x8 a3 = hp[(size_t)s3 * 16 + x];
#pragma unroll
    for (int i = 0; i < 8; i++) acc[i] += bf2f(a0[i]) + bf2f(a1[i]);
#pragma unroll
    for (int i = 0; i < 8; i++) acc[i] += bf2f(a2[i]) + bf2f(a3[i]);
  }
  for (; e < c; e++) {
    u16x8 a0 = hp[(size_t)base[e] * 16 + x];
#pragma unroll
    for (int i = 0; i < 8; i++) acc[i] += bf2f(a0[i]);
  }
  u16x8 r;
#pragma unroll
  for (int i = 0; i < 8; i++) r[i] = f2bf(acc[i]);
  reinterpret_cast<u16x8*>(out)[(size_t)node * 16 + x] = r;
}

// ---- MLP in-place: hio = (relu?)(relu(hio@W1^T+b1)@W2^T+b2) ----
// 64 nodes/block, 4 waves. W staged one-at-a-time in 32KB LDS (XOR-swizzled),
// + 16KB per-wave h1 tile = 48KB -> 3 blocks/CU.
__global__ __launch_bounds__(256, 3) void mlp_kernel(
    unsigned short* __restrict__ hio, const unsigned short* __restrict__ W1,
    const float* __restrict__ b1, const unsigned short* __restrict__ W2,
    const float* __restrict__ b2, int N, int relu_out) {
  __shared__ unsigned short Wt[128 * D];   // one weight matrix (32KB)
  __shared__ unsigned short hs[4][16 * D]; // per-wave h1 tile (16KB)
  const int tid = threadIdx.x;
  const int lane = tid & 63;
  const int w = tid >> 6;
  const int c = lane & 15;
  const int q = lane >> 4;

  const int node = blockIdx.x * 64 + w * 16 + c;

  // issue A-frag loads first (overlap with W1 staging)
  bf16x8 afrag[4];
  if (node < N) {
    const bf16x8* hp = reinterpret_cast<const bf16x8*>(hio);
    size_t rb = (size_t)node * 16;
#pragma unroll
    for (int ks = 0; ks < 4; ks++) afrag[ks] = hp[rb + ks * 4 + q];
  } else {
#pragma unroll
    for (int ks = 0; ks < 4; ks++)
#pragma unroll
      for (int i = 0; i < 8; i++) afrag[ks][i] = 0;
  }

  // stage W1 -> LDS, granule swizzle gs = g ^ (row&15)
#pragma unroll
  for (int i = 0; i < 8; i++) {
    int gid = tid + 256 * i;
    int row = gid >> 4;
    int g = gid & 15;
    *reinterpret_cast<u16x8*>(&Wt[row * D + (g ^ (row & 15)) * 8]) =
        *reinterpret_cast<const u16x8*>(W1 + (size_t)row * D + g * 8);
  }
  __syncthreads();

  // GEMM1: B rows j*16+c, granule ks*4+q; swizzle key (j*16+c)&15 == c
  f32x4 acc1[8] = {};
#pragma unroll
  for (int ks = 0; ks < 4; ks++) {
    int g = ks * 4 + q;
#pragma unroll
    for (int j = 0; j < 8; j++) {
      bf16x8 b = *reinterpret_cast<const bf16x8*>(&Wt[(j * 16 + c) * D + ((g ^ c) * 8)]);
      acc1[j] = __builtin_amdgcn_mfma_f32_16x16x32_bf16(afrag[ks], b, acc1[j], 0, 0, 0);
    }
  }

  // h1 = relu(acc1+b1) -> per-wave LDS tile (C-layout -> A-layout shuffle)
  unsigned short* tile = &hs[w][0];
#pragma unroll
  for (int j = 0; j < 8; j++) {
    int col = j * 16 + c;
    float bb = b1[col];
    int gcol = col >> 3;
    int el = col & 7;
#pragma unroll
    for (int r = 0; r < 4; r++) {
      int row = q * 4 + r;  // C/D layout: row = (lane>>4)*4 + reg
      float v = fmaxf(acc1[j][r] + bb, 0.f);
      tile[row * D + ((gcol ^ row) * 8) + el] = f2bf(v);
    }
  }
  __syncthreads();  // all GEMM1 Wt reads + hs writes done

  // stage W2 over Wt
#pragma unroll
  for (int i = 0; i < 8; i++) {
    int gid = tid + 256 * i;
    int row = gid >> 4;
    int g = gid & 15;
    *reinterpret_cast<u16x8*>(&Wt[row * D + (g ^ (row & 15)) * 8]) =
        *reinterpret_cast<const u16x8*>(W2 + (size_t)row * D + g * 8);
  }
  __syncthreads();

  // GEMM2: A from hs tile, B from Wt
  f32x4 acc2[8] = {};
#pragma unroll
  for (int ks = 0; ks < 4; ks++) {
    int g = ks * 4 + q;
    bf16x8 a = *reinterpret_cast<const bf16x8*>(&tile[c * D + ((g ^ c) * 8)]);
#pragma unroll
    for (int j = 0; j < 8; j++) {
      bf16x8 b = *reinterpret_cast<const bf16x8*>(&Wt[(j * 16 + c) * D + ((g ^ c) * 8)]);
      acc2[j] = __builtin_amdgcn_mfma_f32_16x16x32_bf16(a, b, acc2[j], 0, 0, 0);
    }
  }

  // epilogue (in-place; each wave writes only the rows it read)
#pragma unroll
  for (int j = 0; j < 8; j++) {
    int col = j * 16 + c;
    float bb = b2[col];
#pragma unroll
    for (int r = 0; r < 4; r++) {
      int rnode = blockIdx.x * 64 + w * 16 + q * 4 + r;
      if (rnode < N) {
        float v = acc2[j][r] + bb;
        if (relu_out) v = fmaxf(v, 0.f);
        hio[(size_t)rnode * D + col] = f2bf(v);
      }
    }
  }
}

// ---- pool partials: grid (NG, 8); deterministic (no float atomics) ----
__global__ __launch_bounds__(256) void pool_partial(const unsigned short* __restrict__ h,
                                                    const int* __restrict__ batch, int n,
                                                    float* __restrict__ partials,
                                                    float* __restrict__ counts) {
  int g = blockIdx.x;
  int s = blockIdx.y;  // 0..7
  __shared__ int sbeg, send;
  if (threadIdx.x == 0) {
    int lo = 0, hi = n;
    while (lo < hi) { int mid = (lo + hi) >> 1; if (batch[mid] < g) lo = mid + 1; else hi = mid; }
    sbeg = lo;
    hi = n;
    while (lo < hi) { int mid = (lo + hi) >> 1; if (batch[mid] < g + 1) lo = mid + 1; else hi = mid; }
    send = lo;
    if (s == 0) counts[g] = (float)(send - sbeg);
  }
  __syncthreads();
  int beg = sbeg, end = send;
  int x = threadIdx.x & 15;
  int ty = threadIdx.x >> 4;  // 0..15
  const u16x8* hp = reinterpret_cast<const u16x8*>(h);
  float acc[8] = {};
  for (int i = beg + s * 16 + ty; i < end; i += 128) {
    u16x8 v = hp[(size_t)i * 16 + x];
#pragma unroll
    for (int k = 0; k < 8; k++) acc[k] += bf2f(v[k]);
  }
  __shared__ float red[16][16][8];
#pragma unroll
  for (int k = 0; k < 8; k++) red[ty][x][k] = acc[k];
  __syncthreads();
  for (int st = 8; st > 0; st >>= 1) {
    if (ty < st) {
#pragma unroll
      for (int k = 0; k < 8; k++) red[ty][x][k] += red[ty + st][x][k];
    }
    __syncthreads();
  }
  if (ty == 0) {
#pragma unroll
    for (int k = 0; k < 8; k++)
      partials[((size_t)s * NG + g) * D + x * 8 + k] = red[0][x][k];
  }
}

__global__ __launch_bounds__(256) void pool_final(const float* __restrict__ partials,
                                                  const float* __restrict__ counts,
                                                  float* __restrict__ out) {
  int idx = blockIdx.x * 256 + threadIdx.x;
  if (idx >= NG * D) return;
  int g = idx >> 7;
  int d = idx & 127;
  float sum = 0.f;
#pragma unroll
  for (int s = 0; s < 8; s++) sum += partials[((size_t)s * NG + g) * D + d];
  out[idx] = sum / fmaxf(counts[g], 1.0f);
}

extern "C" void kernel_launch(void* const* d_in, const int* in_sizes, int n_in,
                              void* d_out, int out_size, void* d_ws, size_t ws_size,
                              hipStream_t stream) {
  const float* x = (const float*)d_in[0];
  const int* ei = (const int*)d_in[1];
  const int* batch = (const int*)d_in[2];
  const float* w[6] = {(const float*)d_in[3], (const float*)d_in[5],
                       (const float*)d_in[7], (const float*)d_in[9],
                       (const float*)d_in[11], (const float*)d_in[13]};
  const float* b[6] = {(const float*)d_in[4], (const float*)d_in[6],
                       (const float*)d_in[8], (const float*)d_in[10],
                       (const float*)d_in[12], (const float*)d_in[14]};
  const int N = in_sizes[0] / D;
  const int E = in_sizes[1] / 2;
  const int* src = ei;
  const int* dst = ei + E;

  char* ws = (char*)d_ws;
  size_t off = 0;
  auto carve = [&](size_t bytes) -> char* {
    char* p = ws + off;
    off = (off + bytes + 255) & ~(size_t)255;
    return p;
  };
  unsigned short* hA = (unsigned short*)carve((size_t)N * D * 2);
  unsigned short* hB = (unsigned short*)carve((size_t)N * D * 2);
  unsigned short* qw = (unsigned short*)carve(6 * D * D * 2);
  int* cnt = (int*)carve((size_t)N * 4);
  int* esrc = (int*)carve((size_t)N * SLOTS * 4);
  float* partials = (float*)carve((size_t)8 * NG * D * 4);
  float* counts = (float*)carve((size_t)NG * 4);
  if (off > ws_size) return;

  // 1) prep: quant weights, zero cnt, convert x->bf16
  int n8 = N * D / 8;
  int prepGrid = (n8 + 255) / 256;
  if (prepGrid < 6) prepGrid = 6;
  int nzGrid = (N + 255) / 256;
  if (prepGrid < nzGrid) prepGrid = nzGrid;
  prep_kernel<<<prepGrid, 256, 0, stream>>>(x, hA, n8, w[0], w[1], w[2], w[3], w[4], w[5], qw, cnt, N);

  // 2) slot-bucket build (standalone, XCD-partitioned)
  int bGrid = ((E + 255) / 256 + 7) & ~7;
  int per_team = (N + 7) / 8;
  build_kernel<<<bGrid, 256, 0, stream>>>(dst, src, cnt, esrc, E, per_team);

  // 3) 3 layers: aggregate (ping-pong) then MLP in-place
  dim3 aggBlock(16, 16);
  int aggGrid = (N + 15) / 16;
  int mlpGrid = (N + 63) / 64;
  unsigned short* cur = hA;
  unsigned short* oth = hB;
  for (int l = 0; l < 3; ++l) {
    aggregate_kernel<<<aggGrid, aggBlock, 0, stream>>>(cur, cnt, esrc, oth, N);
    mlp_kernel<<<mlpGrid, 256, 0, stream>>>(oth, qw + (size_t)(2 * l) * D * D, b[2 * l],
                                            qw + (size_t)(2 * l + 1) * D * D, b[2 * l + 1], N,
                                            (l < 2) ? 1 : 0);
    unsigned short* t = cur; cur = oth; oth = t;
  }

  // 4) pool: deterministic partials + finalize
  dim3 ppGrid(NG, 8);
  pool_partial<<<ppGrid, 256, 0, stream>>>(cur, batch, N, partials, counts);
  pool_final<<<(NG * D + 255) / 256, 256, 0, stream>>>(partials, counts, (float*)d_out);
}